// Round 5
// baseline (93.991 us; speedup 1.0000x reference)
//
#include <hip/hip_runtime.h>
#include <math.h>

#define H   128
#define NS  1024
#define NE  512
#define M   1024

typedef float v2f __attribute__((ext_vector_type(2)));
__device__ __forceinline__ v2f splat(float x) { return (v2f){x, x}; }

__device__ __forceinline__ float fast_tanh(float x) {   // for k_final only
    float e = __expf(2.0f * x);
    float r = __builtin_amdgcn_rcpf(1.0f + e);
    return 1.0f - 2.0f * r;
}

// ---- transpose the weight matrices (no scale: Pade tanh takes raw arg) ----
__global__ __launch_bounds__(256) void k_tr(const float* __restrict__ Wc_s,
                                            const float* __restrict__ Wc_e,
                                            const float* __restrict__ W_lin,
                                            float* __restrict__ WT_s1, float* __restrict__ WT_s2,
                                            float* __restrict__ WT_e1, float* __restrict__ WT_e2,
                                            float* __restrict__ WT_lin) {
    int idx = blockIdx.x * 256 + threadIdx.x;
    if (idx < 65536) {
        int t = idx >> 14, r = idx & 16383, k = r >> 7, hh = r & 127;
        const float* src = (t < 2) ? Wc_s : Wc_e;
        int off = (t & 1) * H;
        float v = src[hh * 256 + off + k];
        float* dst = (t == 0) ? WT_s1 : (t == 1) ? WT_s2 : (t == 2) ? WT_e1 : WT_e2;
        dst[r] = v;
    } else {
        int j2 = idx - 65536;             // [0, 49152)
        int k = j2 >> 7, a = j2 & 127;
        WT_lin[j2] = W_lin[a * 384 + k];
    }
}

// ---- all four projections; split-k x2 for latency ------------------------
__global__ __launch_bounds__(256) void k_proj(const float* __restrict__ stmts,
                                              const float* __restrict__ eres,
                                              const float* __restrict__ attender,
                                              const float* __restrict__ WT_s1,
                                              const float* __restrict__ WT_s2,
                                              const float* __restrict__ WT_e1,
                                              const float* __restrict__ WT_e2,
                                              const float* __restrict__ bc_s,
                                              const float* __restrict__ bc_e,
                                              float* __restrict__ A_s, float* __restrict__ B_s,
                                              float* __restrict__ A_e, float* __restrict__ B_e) {
    int b = blockIdx.x;
    const float *X, *WT, *bias; float* O; int r0;
    if (b < 256)      { X = stmts;    WT = WT_s1; bias = bc_s;    O = A_s; r0 = b * 4; }
    else if (b < 512) { X = attender; WT = WT_s2; bias = nullptr; O = B_s; r0 = (b - 256) * 4; }
    else if (b < 640) { X = eres;     WT = WT_e1; bias = bc_e;    O = A_e; r0 = (b - 512) * 4; }
    else              { X = attender; WT = WT_e2; bias = nullptr; O = B_e; r0 = (b - 640) * 4; }
    __shared__ float xr[4][H];
    __shared__ float red[4][H];
    int tid  = threadIdx.x;
    int t    = tid & 127;
    int half = tid >> 7;
    float* xf = &xr[0][0];
    xf[tid]       = X[r0 * H + tid];
    xf[tid + 256] = X[r0 * H + 256 + tid];
    __syncthreads();
    float b0 = (bias && half == 0) ? bias[t] : 0.0f;
    float acc[4] = {b0, b0, b0, b0};
    int k0 = half * 64;
    #pragma unroll 8
    for (int k = k0; k < k0 + 64; ++k) {
        float wv = WT[k * H + t];
        #pragma unroll
        for (int r = 0; r < 4; ++r) acc[r] += xr[r][k] * wv;
    }
    if (half) {
        #pragma unroll
        for (int r = 0; r < 4; ++r) red[r][t] = acc[r];
    }
    __syncthreads();
    if (!half) {
        #pragma unroll
        for (int r = 0; r < 4; ++r) O[(r0 + r) * H + t] = acc[r] + red[r][t];
    }
}

// ---- scores: St[m][n] = sum_h ws[h] * tanh_pade(A[n,h] + B[m,h]) ----------
// Pade [5/4]: tanh(x) ~= x(945+105x^2+x^4)/(945+420x^2+15x^4), |x| clamped to 4
// (max err 2.3e-3). Packed f32 pairs (v_pk_*), one v_rcp per element, no exp.
__global__ __launch_bounds__(256, 6) void k_score(const float* __restrict__ A_s,
                                                  const float* __restrict__ B_s,
                                                  const float* __restrict__ ws_s,
                                                  const float* __restrict__ A_e,
                                                  const float* __restrict__ B_e,
                                                  const float* __restrict__ ws_e,
                                                  float* __restrict__ St_s,
                                                  float* __restrict__ St_e) {
    __shared__ float Bs[32 * H];   // 16 KB
    int bx = blockIdx.x;
    const float *A, *B, *wsv; float* St; int N, n0;
    if (bx < 32) { A = A_s; B = B_s; wsv = ws_s; St = St_s; N = NS; n0 = bx * 32; }
    else         { A = A_e; B = B_e; wsv = ws_e; St = St_e; N = NE; n0 = (bx - 32) * 32; }
    int m0 = blockIdx.y * 32;
    int tid = threadIdx.x;

    #pragma unroll
    for (int i = 0; i < 4; ++i) {
        int idx = tid + i * 256;
        float4 v = *(const float4*)(B + (size_t)m0 * H + idx * 4);
        *(float4*)(Bs + idx * 4) = v;
    }
    __syncthreads();

    int tn  = tid & 31;
    int tm4 = tid >> 5;            // 0..7
    const float* Arow = A + (size_t)(n0 + tn) * H;
    v2f acc2[4] = {splat(0.f), splat(0.f), splat(0.f), splat(0.f)};

    #pragma unroll 2
    for (int h0 = 0; h0 < H; h0 += 8) {
        v2f a2[4], w2[4];
        const v2f* ar = (const v2f*)(Arow + h0);
        const v2f* wr = (const v2f*)(wsv + h0);
        #pragma unroll
        for (int kk = 0; kk < 4; ++kk) { a2[kk] = ar[kk]; w2[kk] = wr[kk]; }
        v2f bf[4][4];
        #pragma unroll
        for (int j = 0; j < 4; ++j) {
            const v2f* br = (const v2f*)(Bs + (tm4 + 8 * j) * H + h0);
            #pragma unroll
            for (int kk = 0; kk < 4; ++kk) bf[j][kk] = br[kk];
        }
        #pragma unroll
        for (int kk = 0; kk < 4; ++kk) {
            #pragma unroll
            for (int j = 0; j < 4; ++j) {
                v2f u = a2[kk] + bf[j][kk];
                u = __builtin_elementwise_max(u, splat(-4.0f));
                u = __builtin_elementwise_min(u, splat( 4.0f));
                v2f t   = u * u;
                v2f num = u * __builtin_elementwise_fma(t, t + splat(105.0f), splat(945.0f));
                v2f q   = __builtin_elementwise_fma(
                              t, __builtin_elementwise_fma(t, splat(15.0f), splat(420.0f)),
                              splat(945.0f));
                v2f r;
                r.x = __builtin_amdgcn_rcpf(q.x);
                r.y = __builtin_amdgcn_rcpf(q.y);
                acc2[j] = __builtin_elementwise_fma(w2[kk] * num, r, acc2[j]);
            }
        }
    }
    #pragma unroll
    for (int j = 0; j < 4; ++j)
        St[(size_t)(m0 + tm4 + 8 * j) * N + n0 + tn] = acc2[j].x + acc2[j].y;
}

// ---- fused softmax-stats + context + final MLP ---------------------------
#define TMD 4
__device__ __forceinline__ void reduce4(float v[TMD], bool domax, float (*scr)[TMD]) {
    #pragma unroll
    for (int off = 32; off > 0; off >>= 1) {
        #pragma unroll
        for (int j = 0; j < TMD; ++j) {
            float o = __shfl_xor(v[j], off, 64);
            v[j] = domax ? fmaxf(v[j], o) : (v[j] + o);
        }
    }
    int wv = threadIdx.x >> 6;     // 0..15
    if ((threadIdx.x & 63) == 0) {
        #pragma unroll
        for (int j = 0; j < TMD; ++j) scr[wv][j] = v[j];
    }
    __syncthreads();
    #pragma unroll
    for (int j = 0; j < TMD; ++j) {
        float r = scr[0][j];
        #pragma unroll
        for (int i = 1; i < 16; ++i) r = domax ? fmaxf(r, scr[i][j]) : (r + scr[i][j]);
        v[j] = r;
    }
    __syncthreads();
}

__global__ __launch_bounds__(1024) void k_attend(const float* __restrict__ St_s,
                                                 const float* __restrict__ St_e,
                                                 const float* __restrict__ stmts,
                                                 const float* __restrict__ eres,
                                                 const float* __restrict__ attender,
                                                 const float* __restrict__ WT_lin,
                                                 const float* __restrict__ b_lin,
                                                 const float* __restrict__ W_coh,
                                                 const float* __restrict__ b_coh,
                                                 float* __restrict__ out) {
    __shared__ float wls[1024][TMD];       // 16 KB, 16B rows: b128 in/out
    __shared__ float part[8][TMD][H];
    __shared__ float feats[TMD][3 * H];
    __shared__ float scr[16][TMD];
    __shared__ float redv[512];
    __shared__ float red8[8];
    int m0  = blockIdx.x * TMD;
    int tid = threadIdx.x;
    int h   = tid & (H - 1);
    int g   = tid >> 7;    // 0..7

    if (tid < TMD * H) feats[tid >> 7][tid & (H - 1)] = attender[(m0 + (tid >> 7)) * H + (tid & (H - 1))];

    float vs[TMD], ve[TMD];
    #pragma unroll
    for (int j = 0; j < TMD; ++j) vs[j] = St_s[(size_t)(m0 + j) * NS + tid];
    #pragma unroll
    for (int j = 0; j < TMD; ++j) ve[j] = (tid < NE) ? St_e[(size_t)(m0 + j) * NE + tid] : -1e30f;

    float mxs[TMD], sm_s[TMD], rz_s[TMD], w_s[TMD];
    #pragma unroll
    for (int j = 0; j < TMD; ++j) mxs[j] = vs[j];
    reduce4(mxs, true, scr);
    #pragma unroll
    for (int j = 0; j < TMD; ++j) { w_s[j] = __expf(vs[j] - mxs[j]); sm_s[j] = w_s[j]; }
    reduce4(sm_s, false, scr);
    #pragma unroll
    for (int j = 0; j < TMD; ++j) rz_s[j] = __builtin_amdgcn_rcpf(sm_s[j]);

    float mxe[TMD], sm_e[TMD], rz_e[TMD], w_e[TMD];
    #pragma unroll
    for (int j = 0; j < TMD; ++j) mxe[j] = ve[j];
    reduce4(mxe, true, scr);
    #pragma unroll
    for (int j = 0; j < TMD; ++j) { w_e[j] = __expf(ve[j] - mxe[j]); sm_e[j] = w_e[j]; }
    reduce4(sm_e, false, scr);
    #pragma unroll
    for (int j = 0; j < TMD; ++j) rz_e[j] = __builtin_amdgcn_rcpf(sm_e[j]);

    // ---- ctx_s ----
    *(float4*)&wls[tid][0] = make_float4(w_s[0], w_s[1], w_s[2], w_s[3]);
    __syncthreads();
    {
        float acc[TMD] = {0.f, 0.f, 0.f, 0.f};
        const float* Xb = stmts + (size_t)(g * 128) * H + h;
        #pragma unroll 8
        for (int nn = 0; nn < 128; ++nn) {
            float x = Xb[(size_t)nn * H];
            float4 w4 = *(const float4*)&wls[g * 128 + nn][0];
            acc[0] += w4.x * x; acc[1] += w4.y * x;
            acc[2] += w4.z * x; acc[3] += w4.w * x;
        }
        #pragma unroll
        for (int j = 0; j < TMD; ++j) part[g][j][h] = acc[j];
    }
    __syncthreads();
    if (tid < 512) {
        int j = tid >> 7, hh = tid & 127;
        float s = 0.f;
        #pragma unroll
        for (int gg = 0; gg < 8; ++gg) s += part[gg][j][hh];
        feats[j][H + hh] = s * rz_s[j];
    }
    __syncthreads();

    // ---- ctx_e ----
    *(float4*)&wls[tid][0] = make_float4(w_e[0], w_e[1], w_e[2], w_e[3]);
    __syncthreads();
    {
        float acc[TMD] = {0.f, 0.f, 0.f, 0.f};
        const float* Xb = eres + (size_t)(g * 64) * H + h;
        #pragma unroll 8
        for (int nn = 0; nn < 64; ++nn) {
            float x = Xb[(size_t)nn * H];
            float4 w4 = *(const float4*)&wls[g * 64 + nn][0];
            acc[0] += w4.x * x; acc[1] += w4.y * x;
            acc[2] += w4.z * x; acc[3] += w4.w * x;
        }
        #pragma unroll
        for (int j = 0; j < TMD; ++j) part[g][j][h] = acc[j];
    }
    __syncthreads();
    if (tid < 512) {
        int j = tid >> 7, hh = tid & 127;
        float s = 0.f;
        #pragma unroll
        for (int gg = 0; gg < 8; ++gg) s += part[gg][j][hh];
        feats[j][2 * H + hh] = s * rz_e[j];
    }
    __syncthreads();

    // ---- final MLP + coherence ----
    {
        int a    = tid & 127;
        int jm   = (tid >> 7) & 3;
        int half = tid >> 9;
        float acc = half ? 0.f : b_lin[a];
        int k0 = half * 192;
        #pragma unroll 8
        for (int k = k0; k < k0 + 192; ++k)
            acc += feats[jm][k] * WT_lin[k * H + a];
        if (half) redv[tid & 511] = acc;
        __syncthreads();
        if (!half) {
            acc += redv[tid];
            float v = fast_tanh(acc) * W_coh[a];
            #pragma unroll
            for (int off = 32; off > 0; off >>= 1) v += __shfl_down(v, off, 64);
            if ((tid & 63) == 0) red8[tid >> 6] = v;
        }
        __syncthreads();
        if (tid < TMD) out[m0 + tid] = red8[2 * tid] + red8[2 * tid + 1] + b_coh[0];
    }
}

extern "C" void kernel_launch(void* const* d_in, const int* in_sizes, int n_in,
                              void* d_out, int out_size, void* d_ws, size_t ws_size,
                              hipStream_t stream) {
    const float* stmts    = (const float*)d_in[0];
    const float* eres     = (const float*)d_in[1];
    const float* attender = (const float*)d_in[2];
    const float* Wc_s     = (const float*)d_in[3];
    const float* bc_s     = (const float*)d_in[4];
    const float* ws_s     = (const float*)d_in[5];
    const float* Wc_e     = (const float*)d_in[7];
    const float* bc_e     = (const float*)d_in[8];
    const float* ws_e     = (const float*)d_in[9];
    const float* W_lin    = (const float*)d_in[11];
    const float* b_lin    = (const float*)d_in[12];
    const float* W_coh    = (const float*)d_in[13];
    const float* b_coh    = (const float*)d_in[14];
    float* out = (float*)d_out;

    float* ws    = (float*)d_ws;
    float* WT_s1 = ws;
    float* WT_s2 = WT_s1 + H * H;
    float* WT_e1 = WT_s2 + H * H;
    float* WT_e2 = WT_e1 + H * H;
    float* WT_li = WT_e2 + H * H;             // 384*128
    float* A_s   = WT_li + 3 * H * H;
    float* B_s   = A_s + NS * H;
    float* A_e   = B_s + M * H;
    float* B_e   = A_e + NE * H;
    float* St_s  = B_e + M * H;
    float* St_e  = St_s + (size_t)M * NS;

    k_tr<<<448, 256, 0, stream>>>(Wc_s, Wc_e, W_lin, WT_s1, WT_s2, WT_e1, WT_e2, WT_li);
    k_proj<<<896, 256, 0, stream>>>(stmts, eres, attender, WT_s1, WT_s2, WT_e1, WT_e2,
                                    bc_s, bc_e, A_s, B_s, A_e, B_e);
    k_score<<<dim3(48, 32), 256, 0, stream>>>(A_s, B_s, ws_s, A_e, B_e, ws_e, St_s, St_e);
    k_attend<<<M / TMD, 1024, 0, stream>>>(St_s, St_e, stmts, eres, attender, WT_li,
                                           b_lin, W_coh, b_coh, out);
}